// Round 7
// baseline (1246.418 us; speedup 1.0000x reference)
//
#include <hip/hip_runtime.h>
#include <math.h>

#define NEGV -1e32f

typedef __bf16 bf16_t;
typedef _Float16 f16_t;
typedef __bf16 bf16x8 __attribute__((ext_vector_type(8)));
typedef __bf16 bf16x4 __attribute__((ext_vector_type(4)));
typedef _Float16 f16x8 __attribute__((ext_vector_type(8)));
typedef float floatx4 __attribute__((ext_vector_type(4)));

// ---------------- fast-math helpers (native transcendental pipe) ----------------
static __device__ __forceinline__ float fexp(float x) { return __expf(x); }  // v_exp_f32
#if __has_builtin(__builtin_amdgcn_sqrtf)
static __device__ __forceinline__ float fsqrt(float x) { return __builtin_amdgcn_sqrtf(x); }
#else
static __device__ __forceinline__ float fsqrt(float x) { return sqrtf(x); }
#endif
#if __has_builtin(__builtin_amdgcn_rcpf)
static __device__ __forceinline__ float frcp(float x) { return __builtin_amdgcn_rcpf(x); }
#else
static __device__ __forceinline__ float frcp(float x) { return 1.0f / x; }
#endif

// ---------------- wave helpers ----------------
static __device__ __forceinline__ float wave_sum(float v) {
#pragma unroll
  for (int d = 32; d > 0; d >>= 1) v += __shfl_xor(v, d, 64);
  return v;
}
static __device__ __forceinline__ float wave_max(float v) {
#pragma unroll
  for (int d = 32; d > 0; d >>= 1) v = fmaxf(v, __shfl_xor(v, d, 64));
  return v;
}

// async global->LDS, 16B per lane; LDS dest is wave-uniform base + lane*16
static __device__ __forceinline__ void gl2lds16(const bf16_t* g, bf16_t* l) {
  __builtin_amdgcn_global_load_lds((__attribute__((address_space(1))) void*)(void*)g,
                                   (__attribute__((address_space(3))) void*)l, 16, 0, 0);
}

// ---------------- phased pipelined GEMM (R2-verified schedule; FFN1 74.4us) --------
// Double-buffered LDS + counted vmcnt: header stages 2 rounds of tile t+1 then
// vmcnt(2); remaining rounds spread across phases. Phase: {ds_read frag subtile |
// stage slice | lgkmcnt(0) | setprio MFMA | barrier}. vmcnt never drains mid-loop.
// Swizzle: slot s of row r holds k-group s ^ (r&7), applied on the GLOBAL source
// column so global_load_lds stays lane-contiguous. Conflict-free (measured 0).
// BIAS_MODE: 0 none, 1 per-col(n), 2 per-row(m). OUT_MODE: 0 fp32, 1 bf16, 2 fp16.
template <int WM, int WN, int FM, int FN, int BIAS_MODE, bool RELU, int OUT_MODE>
__global__ __launch_bounds__(WM * WN * 64) void gemm_db(
    const bf16_t* __restrict__ A, long lda, long a_so, long a_si,
    const bf16_t* __restrict__ B, long ldb, long b_so, long b_si,
    void* __restrict__ Cv, long ldc, long c_so, long c_si,
    const float* __restrict__ bias, int zdiv, int K, float alpha)
{
  constexpr int THREADS = WM * WN * 64;
  constexpr int BM = WM * FM * 16;
  constexpr int BN = WN * FN * 16;
  constexpr int RR = THREADS / 8;
  constexpr int RA = BM / RR;
  constexpr int RB = BN / RR;
  constexpr int NSTG = RA + RB;
  constexpr int MG = (FM >= 8) ? 2 : 1;
  constexpr int MSUB = FM / MG;
  constexpr int PH = 2 * MG;
  extern __shared__ bf16_t smem[];
  bf16_t* const Asb = smem;                    // [2][BM*64]
  bf16_t* const Bsb = smem + 2 * (BM * 64);    // [2][BN*64]

  const int tid = threadIdx.x;
  const int wave = tid >> 6;
  const int lane = tid & 63;
  const int wm = wave / WN;
  const int wn = wave % WN;
  const int z = blockIdx.z;
  const long zo = z / zdiv;
  const long zi = z % zdiv;
  A += zo * a_so + zi * a_si;
  B += zo * b_so + zi * b_si;
  const long m0 = (long)blockIdx.x * BM;
  const long n0 = (long)blockIdx.y * BN;

  const int srow = tid >> 3;
  const int scol = ((tid & 7) ^ (srow & 7)) * 8;
  const bf16_t* gA = A + (m0 + srow) * lda + scol;
  const bf16_t* gB = B + (n0 + srow) * ldb + scol;
  const int lofs = wave * 512;

  floatx4 acc[FM][FN] = {};
  const int lr = lane & 15;
  const int kg = lane >> 4;
  const int NT = K >> 6;

  auto stage_round = [&](int q, long ko, int dstbuf) {
    if (q < RA)
      gl2lds16(gA + (long)(q * RR) * lda + ko,
               Asb + dstbuf * (BM * 64) + lofs + q * RR * 64);
    else
      gl2lds16(gB + (long)((q - RA) * RR) * ldb + ko,
               Bsb + dstbuf * (BN * 64) + lofs + (q - RA) * RR * 64);
  };

  // prologue: tile 0 -> buf 0
#pragma unroll
  for (int q = 0; q < NSTG; ++q) stage_round(q, 0, 0);

  for (int t = 0; t < NT; ++t) {
    const int buf = t & 1;
    const bool pf = (t + 1 < NT);
    const long ko = (long)(t + 1) * 64;
    if (pf) {
#pragma unroll
      for (int q = 0; q < 2; ++q) stage_round(q, ko, buf ^ 1);
      asm volatile("s_waitcnt vmcnt(2)" ::: "memory");
    } else {
      asm volatile("s_waitcnt vmcnt(0)" ::: "memory");
    }
    __builtin_amdgcn_s_barrier();
    __builtin_amdgcn_sched_barrier(0);
    const bf16_t* __restrict__ Ab = Asb + buf * (BM * 64);
    const bf16_t* __restrict__ Bb = Bsb + buf * (BN * 64);
#pragma unroll
    for (int h = 0; h < 2; ++h) {
      const int slot = ((h * 4 + kg) ^ (lr & 7)) * 8;
      bf16x8 bfr[FN];
#pragma unroll
      for (int g = 0; g < MG; ++g) {
        const int pi = h * MG + g;
        bf16x8 af[MSUB];
#pragma unroll
        for (int m = 0; m < MSUB; ++m)
          af[m] = *(const bf16x8*)(Ab + (wm * (FM * 16) + (g * MSUB + m) * 16 + lr) * 64 + slot);
        if (g == 0) {
#pragma unroll
          for (int n = 0; n < FN; ++n)
            bfr[n] = *(const bf16x8*)(Bb + (wn * (FN * 16) + n * 16 + lr) * 64 + slot);
        }
        if (pf) {
          const int q0 = 2 + pi * 6 / PH;
          const int q1 = 2 + (pi + 1) * 6 / PH;
#pragma unroll
          for (int q = q0; q < q1; ++q) stage_round(q, ko, buf ^ 1);
        }
        asm volatile("s_waitcnt lgkmcnt(0)" ::: "memory");
        __builtin_amdgcn_sched_barrier(0);
        __builtin_amdgcn_s_setprio(1);
#pragma unroll
        for (int m = 0; m < MSUB; ++m)
#pragma unroll
          for (int n = 0; n < FN; ++n)
            acc[g * MSUB + m][n] =
                __builtin_amdgcn_mfma_f32_16x16x32_bf16(af[m], bfr[n], acc[g * MSUB + m][n], 0, 0, 0);
        __builtin_amdgcn_s_setprio(0);
        __builtin_amdgcn_sched_barrier(0);
        __builtin_amdgcn_s_barrier();
      }
    }
  }

  // epilogue: C/D layout col=lane&15, row=(lane>>4)*4+reg (m89-verified)
  const long coff = zo * c_so + zi * c_si;
  const int q4 = (lane >> 4) * 4;
#pragma unroll
  for (int m = 0; m < FM; ++m) {
#pragma unroll
    for (int n = 0; n < FN; ++n) {
#pragma unroll
      for (int r = 0; r < 4; ++r) {
        const long row = m0 + wm * (FM * 16) + m * 16 + q4 + r;
        const long col = n0 + wn * (FN * 16) + n * 16 + lr;
        float v = acc[m][n][r] * alpha;
        if (BIAS_MODE == 1) v += bias[col];
        if (BIAS_MODE == 2) v += bias[row];
        if (RELU) v = fmaxf(v, 0.0f);
        const long idx = coff + row * ldc + col;
        if (OUT_MODE == 1)      ((bf16_t*)Cv)[idx] = (bf16_t)v;
        else if (OUT_MODE == 2) ((f16_t*)Cv)[idx]  = (f16_t)v;
        else                    ((float*)Cv)[idx]  = v;
      }
    }
  }
}

// ---------------- fused attention v3: 8 waves/block, all-register QK^T / PV --------
// One block = (b,h, 32-row Q-block), 512 threads. Wave w owns: keys w*64..w*64+63 in
// QK^T (acc[2][4] = 32 VGPR, half of v2's 64 -> under the 64-VGPR occupancy cliff),
// 4 softmax rows (half the serial chain of v2), cols w*16..w*16+15 in PV.
// Q/K/V fragments load directly from global (L2-resident; zero reuse across waves ->
// LDS staging would only add barriers). Only S (32x512 fp16 = 32 KB) is in LDS,
// granule-XOR swizzled: logical 16B granule g of row r at phys g^(r&7). LDS 32KB ->
// 4 blocks x 8 waves = 32 waves/CU ceiling; launch_bounds(512,8) forces VGPR<=64.
// Barriers per block: 2. Softmax math byte-identical to the verified attn_mid.
__global__ __launch_bounds__(512, 8) void attn_fused(
    const bf16_t* __restrict__ KQ,   // (B,S,H,DK): row stride 1024, head off h*128
    const bf16_t* __restrict__ VT,   // per b: [H*DK][512] d-major, head off h*65536
    bf16_t* __restrict__ ATT,        // (B,S,H*DK)
    const int* __restrict__ bbit_l, const float* __restrict__ gam,
    const int bmask, const int zero_pad)
{
  __shared__ f16_t Sp16[32 * 512];            // S (fp16) then P (bf16 view), swizzled
  bf16_t* const SpB = (bf16_t*)Sp16;

  const int tid = threadIdx.x;
  const int wave = tid >> 6;                  // 0..7
  const int lane = tid & 63;
  const int lr = lane & 15;
  const int kg = lane >> 4;
  // bijective XCD-chunk swizzle: 2048 wgs, XCD k owns bh 16k..16k+15
  const int id = blockIdx.x;
  const int wg = (id & 7) * 256 + (id >> 3);
  const int bh = wg >> 4;
  const int qb = wg & 15;
  const int b = bh >> 3, h = bh & 7;
  const bf16_t* Qp = KQ + (long)b * 524288 + h * 128 + (long)qb * 32 * 1024;
  const bf16_t* Kp = KQ + (long)b * 524288 + h * 128;
  const bf16_t* Vp = VT + (long)b * 524288 + (long)h * 65536;

  // ---- phase 1: S[:, w*64 .. w*64+63] = Q K^T, all-register, no barriers ----
  const int kb0 = wave * 64;
  floatx4 acc[2][4] = {};
#pragma unroll
  for (int kt = 0; kt < 2; ++kt) {
#pragma unroll
    for (int hh = 0; hh < 2; ++hh) {
      const int co = kt * 64 + (hh * 4 + kg) * 8;
      bf16x8 aq[2], bfr[4];
#pragma unroll
      for (int m = 0; m < 2; ++m)
        aq[m] = *(const bf16x8*)(Qp + (long)(m * 16 + lr) * 1024 + co);
#pragma unroll
      for (int n = 0; n < 4; ++n)
        bfr[n] = *(const bf16x8*)(Kp + (long)(kb0 + n * 16 + lr) * 1024 + co);
#pragma unroll
      for (int m = 0; m < 2; ++m)
#pragma unroll
        for (int n = 0; n < 4; ++n)
          acc[m][n] = __builtin_amdgcn_mfma_f32_16x16x32_bf16(aq[m], bfr[n], acc[m][n], 0, 0, 0);
    }
  }

  // S -> LDS (fp16, scaled, granule-swizzled). row = m*16 + kg*4 + rr (m89 layout).
  const int q4 = kg * 4;
#pragma unroll
  for (int m = 0; m < 2; ++m)
#pragma unroll
    for (int n = 0; n < 4; ++n)
#pragma unroll
      for (int rr = 0; rr < 4; ++rr) {
        const int row = m * 16 + q4 + rr;
        const int col = kb0 + n * 16 + lr;
        const int g = (col >> 3) ^ (row & 7);
        Sp16[row * 512 + g * 8 + (col & 7)] = (f16_t)(acc[m][n][rr] * 0.08838834764831845f);
      }
  __syncthreads();

  // ---- phase 2: verified attn_mid math, 4 rows per wave, LDS in place ----
  {
    const float gamma = -log1pf(fexp(gam[h]));
    const int* bb = bbit_l + h * 512;
#pragma unroll 1
    for (int rr4 = 0; rr4 < 4; ++rr4) {
      const int r = wave * 4 + rr4;
      const int i = qb * 32 + r;
      const int jb = lane * 8;                           // logical cols
      const int ga = r * 512 + ((lane ^ (r & 7)) << 3);  // swizzled addr (16B granule)
      float sv[8];
      {
        const f16x8 a = *(const f16x8*)(Sp16 + ga);
#pragma unroll
        for (int u = 0; u < 8; ++u) sv[u] = (float)a[u];
      }
      float zz[8];
      bool band[8];
      float m1 = NEGV;
#pragma unroll
      for (int u = 0; u < 8; ++u) {
        const int j = jb + u;
        const bool bd = j < i + bmask;
        band[u] = bd;
        int d = j - i; d = d < 0 ? 0 : d;
        const bool allowed = bd || (bb[d] == 0);
        zz[u] = allowed ? sv[u] : NEGV;
        m1 = fmaxf(m1, zz[u]);
      }
      m1 = wave_max(m1);
      float e[8], es = 0.f;
#pragma unroll
      for (int u = 0; u < 8; ++u) { e[u] = fexp(zz[u] - m1); es += e[u]; }
      es = wave_sum(es);
      const float inv1 = frcp(es);
      float c[8];
      float run = 0.f;
#pragma unroll
      for (int u = 0; u < 8; ++u) {
        const float p = band[u] ? e[u] * inv1 : 0.f;
        run += p;
        c[u] = run;
      }
      float x = run;
#pragma unroll
      for (int d = 1; d < 64; d <<= 1) {
        const float y = __shfl_up(x, (unsigned)d, 64);
        if (lane >= d) x += y;
      }
      const float tot = __shfl(x, 63, 64);
      const float ex = x - run;
      float z2[8];
      float m2 = NEGV;
#pragma unroll
      for (int u = 0; u < 8; ++u) {
        const int j = jb + u;
        const float cc = c[u] + ex;
        const float pos = fabsf((float)(i - j));
        const float dist = fsqrt(fmaxf((tot - cc) * pos, 0.f));
        float te = fexp(dist * gamma);
        te = fminf(fmaxf(te, 1e-5f), 1e5f);
        z2[u] = band[u] ? sv[u] * te : NEGV;
        m2 = fmaxf(m2, z2[u]);
      }
      m2 = wave_max(m2);
      float f[8], es2 = 0.f;
#pragma unroll
      for (int u = 0; u < 8; ++u) { f[u] = fexp(z2[u] - m2); es2 += f[u]; }
      es2 = wave_sum(es2);
      const float inv2 = (zero_pad && i == 0) ? 0.f : frcp(es2);
      bf16x8 o;
#pragma unroll
      for (int u = 0; u < 8; ++u) o[u] = (bf16_t)(f[u] * inv2);
      *(bf16x8*)(SpB + ga) = o;
    }
  }
  __syncthreads();

  // ---- phase 3: ATT[:, w*16 .. w*16+15] = P V^T; P from LDS, V direct global ----
  floatx4 acc2[2] = {};
#pragma unroll 1
  for (int kt = 0; kt < 8; ++kt) {
#pragma unroll
    for (int hh = 0; hh < 2; ++hh) {
      const int ks = hh * 4 + kg;
      bf16x8 af[2], bfr;
#pragma unroll
      for (int m = 0; m < 2; ++m) {
        const int g = (kt * 8 + ks) ^ (lr & 7);
        af[m] = *(const bf16x8*)(SpB + (m * 16 + lr) * 512 + g * 8);
      }
      bfr = *(const bf16x8*)(Vp + (long)(wave * 16 + lr) * 512 + kt * 64 + ks * 8);
#pragma unroll
      for (int m = 0; m < 2; ++m)
        acc2[m] = __builtin_amdgcn_mfma_f32_16x16x32_bf16(af[m], bfr, acc2[m], 0, 0, 0);
    }
  }

  // epilogue: ATT(b, qb*32+row, h*128 + wave*16 + lr)
#pragma unroll
  for (int m = 0; m < 2; ++m)
#pragma unroll
    for (int rr = 0; rr < 4; ++rr) {
      const int row = m * 16 + q4 + rr;
      const int col = wave * 16 + lr;
      ATT[(long)b * 524288 + (long)(qb * 32 + row) * 1024 + h * 128 + col] =
          (bf16_t)acc2[m][rr];
    }
}

// ---------------- fp32 -> bf16 cast ----------------
__global__ __launch_bounds__(256) void cast_kernel(const float* __restrict__ in,
                                                   bf16_t* __restrict__ out, long n)
{
  const long i = ((long)blockIdx.x * 256 + threadIdx.x) * 4;
  if (i >= n) return;
  const float4 v = *(const float4*)(in + i);
  bf16x4 o;
  o[0] = (bf16_t)v.x; o[1] = (bf16_t)v.y; o[2] = (bf16_t)v.z; o[3] = (bf16_t)v.w;
  *(bf16x4*)(out + i) = o;
}

// ---------------- gumbel choice bits ----------------
__global__ void bbit_kernel(const float* __restrict__ alphas, const float* __restrict__ E,
                            int* __restrict__ bbit, int n)
{
  const int i = blockIdx.x * 256 + threadIdx.x;
  if (i >= n) return;
  const float l0 = alphas[2 * i]     - logf(E[2 * i]     + 1e-5f);
  const float l1 = alphas[2 * i + 1] - logf(E[2 * i + 1] + 1e-5f);
  bbit[i] = (l0 >= l1) ? 1 : 0;
}

// ---------------- LayerNorm(X + R) * g + b ----------------
template <bool XBF>
__global__ __launch_bounds__(256) void ln_kernel(
    const void* __restrict__ Xv, const float* __restrict__ R,
    const float* __restrict__ g, const float* __restrict__ b,
    float* __restrict__ out32, bf16_t* __restrict__ out16)
{
  const long row = blockIdx.x;
  const int t = threadIdx.x;
  float x0, x1, x2, x3;
  if (XBF) {
    const bf16x4 xv = *(const bf16x4*)((const bf16_t*)Xv + row * 1024 + t * 4);
    x0 = (float)xv[0]; x1 = (float)xv[1]; x2 = (float)xv[2]; x3 = (float)xv[3];
  } else {
    const float4 xv = *(const float4*)((const float*)Xv + row * 1024 + t * 4);
    x0 = xv.x; x1 = xv.y; x2 = xv.z; x3 = xv.w;
  }
  const float4 rv = *(const float4*)(R + row * 1024 + t * 4);
  const float v0 = x0 + rv.x, v1 = x1 + rv.y, v2 = x2 + rv.z, v3 = x3 + rv.w;
  float s  = v0 + v1 + v2 + v3;
  float s2 = v0 * v0 + v1 * v1 + v2 * v2 + v3 * v3;
  s = wave_sum(s); s2 = wave_sum(s2);
  __shared__ float red[8];
  const int wv = t >> 6, lane = t & 63;
  if (lane == 0) { red[wv] = s; red[4 + wv] = s2; }
  __syncthreads();
  s  = red[0] + red[1] + red[2] + red[3];
  s2 = red[4] + red[5] + red[6] + red[7];
  const float mu = s * (1.0f / 1024.0f);
  const float var = s2 * (1.0f / 1024.0f) - mu * mu;
  const float rstd = rsqrtf(var + 1e-5f);
  const float4 gv = *(const float4*)(g + t * 4);
  const float4 bv = *(const float4*)(b + t * 4);
  float4 ov;
  ov.x = (v0 - mu) * rstd * gv.x + bv.x;
  ov.y = (v1 - mu) * rstd * gv.y + bv.y;
  ov.z = (v2 - mu) * rstd * gv.z + bv.z;
  ov.w = (v3 - mu) * rstd * gv.w + bv.w;
  if (out32) *(float4*)(out32 + row * 1024 + t * 4) = ov;
  if (out16) {
    bf16x4 oh;
    oh[0] = (bf16_t)ov.x; oh[1] = (bf16_t)ov.y; oh[2] = (bf16_t)ov.z; oh[3] = (bf16_t)ov.w;
    *(bf16x4*)(out16 + row * 1024 + t * 4) = oh;
  }
}

// ---------------- host ----------------
extern "C" void kernel_launch(void* const* d_in, const int* in_sizes, int n_in,
                              void* d_out, int out_size, void* d_ws, size_t ws_size,
                              hipStream_t stream)
{
  (void)in_sizes; (void)n_in; (void)out_size; (void)ws_size;
  const float* q_emb  = (const float*)d_in[0];
  const float* qa_emb = (const float*)d_in[1];
  const float* kW = (const float*)d_in[2];
  const float* kb = (const float*)d_in[3];
  const float* vW = (const float*)d_in[4];
  const float* vb = (const float*)d_in[5];
  const float* oW = (const float*)d_in[6];
  const float* ob = (const float*)d_in[7];
  const float* gammas = (const float*)d_in[8];
  const float* alphas = (const float*)d_in[9];
  const float* ln1_g = (const float*)d_in[10];
  const float* ln1_b = (const float*)d_in[11];
  const float* w1 = (const float*)d_in[12];
  const float* b1 = (const float*)d_in[13];
  const float* w2 = (const float*)d_in[14];
  const float* b2 = (const float*)d_in[15];
  const float* ln2_g = (const float*)d_in[16];
  const float* ln2_b = (const float*)d_in[17];
  const float* gumE = (const float*)d_in[18];
  float* outp = (float*)d_out;

  static bool attr_done = false;
  if (!attr_done) {
    attr_done = true;
    (void)hipFuncSetAttribute(reinterpret_cast<const void*>(&gemm_db<2,2,4,4,1,false,1>),
                              hipFuncAttributeMaxDynamicSharedMemorySize, 65536);
    (void)hipFuncSetAttribute(reinterpret_cast<const void*>(&gemm_db<2,2,4,4,2,false,1>),
                              hipFuncAttributeMaxDynamicSharedMemorySize, 65536);
    (void)hipFuncSetAttribute(reinterpret_cast<const void*>(&gemm_db<2,2,4,4,1,false,0>),
                              hipFuncAttributeMaxDynamicSharedMemorySize, 65536);
    (void)hipFuncSetAttribute(reinterpret_cast<const void*>(&gemm_db<2,4,8,4,1,true,1>),
                              hipFuncAttributeMaxDynamicSharedMemorySize, 131072);
  }

  // ---- workspace overlay ----
  const size_t MBc = 1ull << 20;
  char* W = (char*)d_ws;
  int*    bbit = (int*)W;
  bf16_t* VB   = (bf16_t*)(W + 1 * MBc);
  bf16_t* XB   = (bf16_t*)(W + 17 * MBc);
  bf16_t* kWb  = (bf16_t*)(W + 33 * MBc);
  bf16_t* vWb  = (bf16_t*)(W + 39 * MBc);
  bf16_t* oWb  = (bf16_t*)(W + 45 * MBc);
  bf16_t* w1b  = (bf16_t*)(W + 51 * MBc);
  bf16_t* w2b  = (bf16_t*)(W + 59 * MBc);
  bf16_t* KQB  = (bf16_t*)(W + 67 * MBc);
  bf16_t* VT   = (bf16_t*)(W + 83 * MBc);
  bf16_t* ATT  = (bf16_t*)(W + 163 * MBc);
  float*  O32  = (float*)(W + 67 * MBc);
  bf16_t* X1B  = (bf16_t*)(W + 99 * MBc);
  bf16_t* H1B  = (bf16_t*)(W + 115 * MBc);

  const long ND = 8388608;  // B*S*D

  auto run_layer = [&](int l, const void* Qin, bool qin_bf16, const bf16_t* XBp,
                       const bf16_t* VBp, bool apply_pos, int bmask,
                       float* o32, bf16_t* o16) {
    const bf16_t* kWl = kWb + (long)l * 1048576;
    const bf16_t* vWl = vWb + (long)l * 1048576;
    const bf16_t* oWl = oWb + (long)l * 1048576;
    // q==k projection -> KQB bf16 (B,S,H,DK)
    gemm_db<2,2,4,4,1,false,1><<<dim3(64, 8, 1), dim3(256), 65536, stream>>>(
        XBp, 1024, 0, 0, kWl, 1024, 0, 0, (void*)KQB, 1024, 0, 0,
        kb + l * 1024, 1, 1024, 1.0f);
    // V^T projection: per batch b, C[d,s] = sum_k vW[d,k]*X[s,k] + vb[d]
    gemm_db<2,2,4,4,2,false,1><<<dim3(8, 4, 16), dim3(256), 65536, stream>>>(
        vWl, 1024, 0, 0, VBp, 1024, 524288, 0, (void*)VT, 512, 524288, 0,
        vb + l * 1024, 1, 1024, 1.0f);
    const int zp = (bmask == 0) ? 1 : 0;
    // fused QK^T -> mid -> PV (S/P never leave LDS; Q/K/V direct from L2)
    attn_fused<<<dim3(2048), dim3(512), 0, stream>>>(
        KQB, VT, ATT, bbit + l * 4096, gammas + l * 8, bmask, zp);
    // output projection -> O32 fp32
    gemm_db<2,2,4,4,1,false,0><<<dim3(64, 8, 1), dim3(256), 65536, stream>>>(
        ATT, 1024, 0, 0, oWl, 1024, 0, 0, (void*)O32, 1024, 0, 0,
        ob + l * 1024, 1, 1024, 1.0f);
    if (!apply_pos) {
      if (qin_bf16)
        ln_kernel<true><<<dim3(8192), dim3(256), 0, stream>>>(
            Qin, O32, ln1_g + l * 1024, ln1_b + l * 1024, o32, o16);
      else
        ln_kernel<false><<<dim3(8192), dim3(256), 0, stream>>>(
            Qin, O32, ln1_g + l * 1024, ln1_b + l * 1024, o32, o16);
    } else {
      cast_kernel<<<dim3(4096), dim3(256), 0, stream>>>(w1 + (long)l * 4194304, w1b, 4194304);
      cast_kernel<<<dim3(4096), dim3(256), 0, stream>>>(w2 + (long)l * 4194304, w2b, 4194304);
      if (qin_bf16)
        ln_kernel<true><<<dim3(8192), dim3(256), 0, stream>>>(
            Qin, O32, ln1_g + l * 1024, ln1_b + l * 1024, nullptr, X1B);
      else
        ln_kernel<false><<<dim3(8192), dim3(256), 0, stream>>>(
            Qin, O32, ln1_g + l * 1024, ln1_b + l * 1024, nullptr, X1B);
      // FFN1: 256x256 tile, 8 waves, 128 KiB LDS
      gemm_db<2,4,8,4,1,true,1><<<dim3(32, 16, 1), dim3(512), 131072, stream>>>(
          X1B, 1024, 0, 0, w1b, 1024, 0, 0, (void*)H1B, 4096, 0, 0,
          b1 + l * 4096, 1, 1024, 1.0f);
      // FFN2: K=4096 deep pipeline
      gemm_db<2,2,4,4,1,false,0><<<dim3(64, 8, 1), dim3(256), 65536, stream>>>(
          H1B, 4096, 0, 0, w2b, 4096, 0, 0, (void*)O32, 1024, 0, 0,
          b2 + l * 1024, 1, 4096, 1.0f);
      ln_kernel<true><<<dim3(8192), dim3(256), 0, stream>>>(
          X1B, O32, ln2_g + l * 1024, ln2_b + l * 1024, o32, o16);
    }
  };

  // upfront: gumbel bits + qkv/o weight casts
  bbit_kernel<<<dim3(48), dim3(256), 0, stream>>>(alphas, gumE, bbit, 12288);
  cast_kernel<<<dim3(3072), dim3(256), 0, stream>>>(kW, kWb, 3145728);
  cast_kernel<<<dim3(3072), dim3(256), 0, stream>>>(vW, vWb, 3145728);
  cast_kernel<<<dim3(3072), dim3(256), 0, stream>>>(oW, oWb, 3145728);

  // layer 0: y = L0(qa, qa, qa), bmask=1, FFN. bf16(y) -> VB (layer2 values).
  cast_kernel<<<dim3(8192), dim3(256), 0, stream>>>(qa_emb, XB, ND);
  run_layer(0, qa_emb, false, XB, XB, true, 1, nullptr, VB);
  // layer 1: x = L1(q, q, q), bmask=1, no FFN. bf16(x) -> XB.
  cast_kernel<<<dim3(8192), dim3(256), 0, stream>>>(q_emb, XB, ND);
  run_layer(1, q_emb, false, XB, XB, false, 1, nullptr, XB);
  // layer 2: out = L2(x, x, y), bmask=0 (zero_pad), FFN.
  run_layer(2, XB, true, XB, VB, true, 0, outp, nullptr);
}

// Round 8
// 1178.932 us; speedup vs baseline: 1.0572x; 1.0572x over previous
//
#include <hip/hip_runtime.h>
#include <math.h>

#define NEGV -1e32f

typedef __bf16 bf16_t;
typedef _Float16 f16_t;
typedef __bf16 bf16x8 __attribute__((ext_vector_type(8)));
typedef __bf16 bf16x4 __attribute__((ext_vector_type(4)));
typedef _Float16 f16x8 __attribute__((ext_vector_type(8)));
typedef float floatx4 __attribute__((ext_vector_type(4)));

// ---------------- fast-math helpers (native transcendental pipe) ----------------
static __device__ __forceinline__ float fexp(float x) { return __expf(x); }  // v_exp_f32
#if __has_builtin(__builtin_amdgcn_sqrtf)
static __device__ __forceinline__ float fsqrt(float x) { return __builtin_amdgcn_sqrtf(x); }
#else
static __device__ __forceinline__ float fsqrt(float x) { return sqrtf(x); }
#endif
#if __has_builtin(__builtin_amdgcn_rcpf)
static __device__ __forceinline__ float frcp(float x) { return __builtin_amdgcn_rcpf(x); }
#else
static __device__ __forceinline__ float frcp(float x) { return 1.0f / x; }
#endif

// ---------------- wave helpers ----------------
static __device__ __forceinline__ float wave_sum(float v) {
#pragma unroll
  for (int d = 32; d > 0; d >>= 1) v += __shfl_xor(v, d, 64);
  return v;
}
static __device__ __forceinline__ float wave_max(float v) {
#pragma unroll
  for (int d = 32; d > 0; d >>= 1) v = fmaxf(v, __shfl_xor(v, d, 64));
  return v;
}

// async global->LDS, 16B per lane; LDS dest is wave-uniform base + lane*16
static __device__ __forceinline__ void gl2lds16(const bf16_t* g, bf16_t* l) {
  __builtin_amdgcn_global_load_lds((__attribute__((address_space(1))) void*)(void*)g,
                                   (__attribute__((address_space(3))) void*)l, 16, 0, 0);
}

// ---------------- phased pipelined GEMM (R2-verified schedule; FFN1 74.4us) --------
// Double-buffered LDS + counted vmcnt: header stages 2 rounds of tile t+1 then
// vmcnt(2); remaining rounds spread across phases. Phase: {ds_read frag subtile |
// stage slice | lgkmcnt(0) | setprio MFMA | barrier}. vmcnt never drains mid-loop.
// Swizzle: slot s of row r holds k-group s ^ (r&7), applied on the GLOBAL source
// column so global_load_lds stays lane-contiguous. Conflict-free (measured 0).
// BIAS_MODE: 0 none, 1 per-col(n), 2 per-row(m). OUT_MODE: 0 fp32, 1 bf16, 2 fp16.
template <int WM, int WN, int FM, int FN, int BIAS_MODE, bool RELU, int OUT_MODE>
__global__ __launch_bounds__(WM * WN * 64) void gemm_db(
    const bf16_t* __restrict__ A, long lda, long a_so, long a_si,
    const bf16_t* __restrict__ B, long ldb, long b_so, long b_si,
    void* __restrict__ Cv, long ldc, long c_so, long c_si,
    const float* __restrict__ bias, int zdiv, int K, float alpha)
{
  constexpr int THREADS = WM * WN * 64;
  constexpr int BM = WM * FM * 16;
  constexpr int BN = WN * FN * 16;
  constexpr int RR = THREADS / 8;
  constexpr int RA = BM / RR;
  constexpr int RB = BN / RR;
  constexpr int NSTG = RA + RB;
  constexpr int MG = (FM >= 8) ? 2 : 1;
  constexpr int MSUB = FM / MG;
  constexpr int PH = 2 * MG;
  extern __shared__ bf16_t smem[];
  bf16_t* const Asb = smem;                    // [2][BM*64]
  bf16_t* const Bsb = smem + 2 * (BM * 64);    // [2][BN*64]

  const int tid = threadIdx.x;
  const int wave = tid >> 6;
  const int lane = tid & 63;
  const int wm = wave / WN;
  const int wn = wave % WN;
  const int z = blockIdx.z;
  const long zo = z / zdiv;
  const long zi = z % zdiv;
  A += zo * a_so + zi * a_si;
  B += zo * b_so + zi * b_si;
  const long m0 = (long)blockIdx.x * BM;
  const long n0 = (long)blockIdx.y * BN;

  const int srow = tid >> 3;
  const int scol = ((tid & 7) ^ (srow & 7)) * 8;
  const bf16_t* gA = A + (m0 + srow) * lda + scol;
  const bf16_t* gB = B + (n0 + srow) * ldb + scol;
  const int lofs = wave * 512;

  floatx4 acc[FM][FN] = {};
  const int lr = lane & 15;
  const int kg = lane >> 4;
  const int NT = K >> 6;

  auto stage_round = [&](int q, long ko, int dstbuf) {
    if (q < RA)
      gl2lds16(gA + (long)(q * RR) * lda + ko,
               Asb + dstbuf * (BM * 64) + lofs + q * RR * 64);
    else
      gl2lds16(gB + (long)((q - RA) * RR) * ldb + ko,
               Bsb + dstbuf * (BN * 64) + lofs + (q - RA) * RR * 64);
  };

  // prologue: tile 0 -> buf 0
#pragma unroll
  for (int q = 0; q < NSTG; ++q) stage_round(q, 0, 0);

  for (int t = 0; t < NT; ++t) {
    const int buf = t & 1;
    const bool pf = (t + 1 < NT);
    const long ko = (long)(t + 1) * 64;
    if (pf) {
#pragma unroll
      for (int q = 0; q < 2; ++q) stage_round(q, ko, buf ^ 1);
      asm volatile("s_waitcnt vmcnt(2)" ::: "memory");
    } else {
      asm volatile("s_waitcnt vmcnt(0)" ::: "memory");
    }
    __builtin_amdgcn_s_barrier();
    __builtin_amdgcn_sched_barrier(0);
    const bf16_t* __restrict__ Ab = Asb + buf * (BM * 64);
    const bf16_t* __restrict__ Bb = Bsb + buf * (BN * 64);
#pragma unroll
    for (int h = 0; h < 2; ++h) {
      const int slot = ((h * 4 + kg) ^ (lr & 7)) * 8;
      bf16x8 bfr[FN];
#pragma unroll
      for (int g = 0; g < MG; ++g) {
        const int pi = h * MG + g;
        bf16x8 af[MSUB];
#pragma unroll
        for (int m = 0; m < MSUB; ++m)
          af[m] = *(const bf16x8*)(Ab + (wm * (FM * 16) + (g * MSUB + m) * 16 + lr) * 64 + slot);
        if (g == 0) {
#pragma unroll
          for (int n = 0; n < FN; ++n)
            bfr[n] = *(const bf16x8*)(Bb + (wn * (FN * 16) + n * 16 + lr) * 64 + slot);
        }
        if (pf) {
          const int q0 = 2 + pi * 6 / PH;
          const int q1 = 2 + (pi + 1) * 6 / PH;
#pragma unroll
          for (int q = q0; q < q1; ++q) stage_round(q, ko, buf ^ 1);
        }
        asm volatile("s_waitcnt lgkmcnt(0)" ::: "memory");
        __builtin_amdgcn_sched_barrier(0);
        __builtin_amdgcn_s_setprio(1);
#pragma unroll
        for (int m = 0; m < MSUB; ++m)
#pragma unroll
          for (int n = 0; n < FN; ++n)
            acc[g * MSUB + m][n] =
                __builtin_amdgcn_mfma_f32_16x16x32_bf16(af[m], bfr[n], acc[g * MSUB + m][n], 0, 0, 0);
        __builtin_amdgcn_s_setprio(0);
        __builtin_amdgcn_sched_barrier(0);
        __builtin_amdgcn_s_barrier();
      }
    }
  }

  // epilogue: C/D layout col=lane&15, row=(lane>>4)*4+reg (m89-verified)
  const long coff = zo * c_so + zi * c_si;
  const int q4 = (lane >> 4) * 4;
#pragma unroll
  for (int m = 0; m < FM; ++m) {
#pragma unroll
    for (int n = 0; n < FN; ++n) {
#pragma unroll
      for (int r = 0; r < 4; ++r) {
        const long row = m0 + wm * (FM * 16) + m * 16 + q4 + r;
        const long col = n0 + wn * (FN * 16) + n * 16 + lr;
        float v = acc[m][n][r] * alpha;
        if (BIAS_MODE == 1) v += bias[col];
        if (BIAS_MODE == 2) v += bias[row];
        if (RELU) v = fmaxf(v, 0.0f);
        const long idx = coff + row * ldc + col;
        if (OUT_MODE == 1)      ((bf16_t*)Cv)[idx] = (bf16_t)v;
        else if (OUT_MODE == 2) ((f16_t*)Cv)[idx]  = (f16_t)v;
        else                    ((float*)Cv)[idx]  = v;
      }
    }
  }
}

// ---------------- fused attention v4: v3 structure, spill-free register budget ----
// One block = (b,h, 32-row Q-block), 512 threads. Wave w owns: keys w*64..w*64+63 in
// QK^T (acc[2][4] = 32 VGPR), 4 softmax rows, cols w*16..w*16+15 in PV.
// v3's launch_bounds(512,8) forced VGPR=32 -> phase-2 softmax (~48 live floats)
// spilled to scratch = 306 MB HBM/dispatch (R7 counters). Fix: (512,4) -> VGPR<=128,
// 2 blocks/CU (16 waves/CU), zero scratch. Q/K/V fragments load directly from global
// (L2-resident; zero cross-wave reuse). Only S (32x512 fp16 = 32 KB) in LDS,
// granule-XOR swizzled (g^(r&7)). Barriers per block: 2. Softmax math byte-identical
// to the verified attn_mid.
__global__ __launch_bounds__(512, 4) void attn_fused(
    const bf16_t* __restrict__ KQ,   // (B,S,H,DK): row stride 1024, head off h*128
    const bf16_t* __restrict__ VT,   // per b: [H*DK][512] d-major, head off h*65536
    bf16_t* __restrict__ ATT,        // (B,S,H*DK)
    const int* __restrict__ bbit_l, const float* __restrict__ gam,
    const int bmask, const int zero_pad)
{
  __shared__ f16_t Sp16[32 * 512];            // S (fp16) then P (bf16 view), swizzled
  bf16_t* const SpB = (bf16_t*)Sp16;

  const int tid = threadIdx.x;
  const int wave = tid >> 6;                  // 0..7
  const int lane = tid & 63;
  const int lr = lane & 15;
  const int kg = lane >> 4;
  // bijective XCD-chunk swizzle: 2048 wgs, XCD k owns bh 16k..16k+15
  const int id = blockIdx.x;
  const int wg = (id & 7) * 256 + (id >> 3);
  const int bh = wg >> 4;
  const int qb = wg & 15;
  const int b = bh >> 3, h = bh & 7;
  const bf16_t* Qp = KQ + (long)b * 524288 + h * 128 + (long)qb * 32 * 1024;
  const bf16_t* Kp = KQ + (long)b * 524288 + h * 128;
  const bf16_t* Vp = VT + (long)b * 524288 + (long)h * 65536;

  // ---- phase 1: S[:, w*64 .. w*64+63] = Q K^T, all-register, no barriers ----
  const int kb0 = wave * 64;
  floatx4 acc[2][4] = {};
#pragma unroll
  for (int kt = 0; kt < 2; ++kt) {
#pragma unroll
    for (int hh = 0; hh < 2; ++hh) {
      const int co = kt * 64 + (hh * 4 + kg) * 8;
      bf16x8 aq[2], bfr[4];
#pragma unroll
      for (int m = 0; m < 2; ++m)
        aq[m] = *(const bf16x8*)(Qp + (long)(m * 16 + lr) * 1024 + co);
#pragma unroll
      for (int n = 0; n < 4; ++n)
        bfr[n] = *(const bf16x8*)(Kp + (long)(kb0 + n * 16 + lr) * 1024 + co);
#pragma unroll
      for (int m = 0; m < 2; ++m)
#pragma unroll
        for (int n = 0; n < 4; ++n)
          acc[m][n] = __builtin_amdgcn_mfma_f32_16x16x32_bf16(aq[m], bfr[n], acc[m][n], 0, 0, 0);
    }
  }

  // S -> LDS (fp16, scaled, granule-swizzled). row = m*16 + kg*4 + rr (m89 layout).
  const int q4 = kg * 4;
#pragma unroll
  for (int m = 0; m < 2; ++m)
#pragma unroll
    for (int n = 0; n < 4; ++n)
#pragma unroll
      for (int rr = 0; rr < 4; ++rr) {
        const int row = m * 16 + q4 + rr;
        const int col = kb0 + n * 16 + lr;
        const int g = (col >> 3) ^ (row & 7);
        Sp16[row * 512 + g * 8 + (col & 7)] = (f16_t)(acc[m][n][rr] * 0.08838834764831845f);
      }
  __syncthreads();

  // ---- phase 2: verified attn_mid math, 4 rows per wave, LDS in place ----
  {
    const float gamma = -log1pf(fexp(gam[h]));
    const int* bb = bbit_l + h * 512;
#pragma unroll 1
    for (int rr4 = 0; rr4 < 4; ++rr4) {
      const int r = wave * 4 + rr4;
      const int i = qb * 32 + r;
      const int jb = lane * 8;                           // logical cols
      const int ga = r * 512 + ((lane ^ (r & 7)) << 3);  // swizzled addr (16B granule)
      float sv[8];
      {
        const f16x8 a = *(const f16x8*)(Sp16 + ga);
#pragma unroll
        for (int u = 0; u < 8; ++u) sv[u] = (float)a[u];
      }
      float zz[8];
      bool band[8];
      float m1 = NEGV;
#pragma unroll
      for (int u = 0; u < 8; ++u) {
        const int j = jb + u;
        const bool bd = j < i + bmask;
        band[u] = bd;
        int d = j - i; d = d < 0 ? 0 : d;
        const bool allowed = bd || (bb[d] == 0);
        zz[u] = allowed ? sv[u] : NEGV;
        m1 = fmaxf(m1, zz[u]);
      }
      m1 = wave_max(m1);
      float e[8], es = 0.f;
#pragma unroll
      for (int u = 0; u < 8; ++u) { e[u] = fexp(zz[u] - m1); es += e[u]; }
      es = wave_sum(es);
      const float inv1 = frcp(es);
      float c[8];
      float run = 0.f;
#pragma unroll
      for (int u = 0; u < 8; ++u) {
        const float p = band[u] ? e[u] * inv1 : 0.f;
        run += p;
        c[u] = run;
      }
      float x = run;
#pragma unroll
      for (int d = 1; d < 64; d <<= 1) {
        const float y = __shfl_up(x, (unsigned)d, 64);
        if (lane >= d) x += y;
      }
      const float tot = __shfl(x, 63, 64);
      const float ex = x - run;
      float z2[8];
      float m2 = NEGV;
#pragma unroll
      for (int u = 0; u < 8; ++u) {
        const int j = jb + u;
        const float cc = c[u] + ex;
        const float pos = fabsf((float)(i - j));
        const float dist = fsqrt(fmaxf((tot - cc) * pos, 0.f));
        float te = fexp(dist * gamma);
        te = fminf(fmaxf(te, 1e-5f), 1e5f);
        z2[u] = band[u] ? sv[u] * te : NEGV;
        m2 = fmaxf(m2, z2[u]);
      }
      m2 = wave_max(m2);
      float f[8], es2 = 0.f;
#pragma unroll
      for (int u = 0; u < 8; ++u) { f[u] = fexp(z2[u] - m2); es2 += f[u]; }
      es2 = wave_sum(es2);
      const float inv2 = (zero_pad && i == 0) ? 0.f : frcp(es2);
      bf16x8 o;
#pragma unroll
      for (int u = 0; u < 8; ++u) o[u] = (bf16_t)(f[u] * inv2);
      *(bf16x8*)(SpB + ga) = o;
    }
  }
  __syncthreads();

  // ---- phase 3: ATT[:, w*16 .. w*16+15] = P V^T; P from LDS, V direct global ----
  floatx4 acc2[2] = {};
#pragma unroll 1
  for (int kt = 0; kt < 8; ++kt) {
#pragma unroll
    for (int hh = 0; hh < 2; ++hh) {
      const int ks = hh * 4 + kg;
      bf16x8 af[2], bfr;
#pragma unroll
      for (int m = 0; m < 2; ++m) {
        const int g = (kt * 8 + ks) ^ (lr & 7);
        af[m] = *(const bf16x8*)(SpB + (m * 16 + lr) * 512 + g * 8);
      }
      bfr = *(const bf16x8*)(Vp + (long)(wave * 16 + lr) * 512 + kt * 64 + ks * 8);
#pragma unroll
      for (int m = 0; m < 2; ++m)
        acc2[m] = __builtin_amdgcn_mfma_f32_16x16x32_bf16(af[m], bfr, acc2[m], 0, 0, 0);
    }
  }

  // epilogue: ATT(b, qb*32+row, h*128 + wave*16 + lr)
#pragma unroll
  for (int m = 0; m < 2; ++m)
#pragma unroll
    for (int rr = 0; rr < 4; ++rr) {
      const int row = m * 16 + q4 + rr;
      const int col = wave * 16 + lr;
      ATT[(long)b * 524288 + (long)(qb * 32 + row) * 1024 + h * 128 + col] =
          (bf16_t)acc2[m][rr];
    }
}

// ---------------- fp32 -> bf16 cast ----------------
__global__ __launch_bounds__(256) void cast_kernel(const float* __restrict__ in,
                                                   bf16_t* __restrict__ out, long n)
{
  const long i = ((long)blockIdx.x * 256 + threadIdx.x) * 4;
  if (i >= n) return;
  const float4 v = *(const float4*)(in + i);
  bf16x4 o;
  o[0] = (bf16_t)v.x; o[1] = (bf16_t)v.y; o[2] = (bf16_t)v.z; o[3] = (bf16_t)v.w;
  *(bf16x4*)(out + i) = o;
}

// ---------------- gumbel choice bits ----------------
__global__ void bbit_kernel(const float* __restrict__ alphas, const float* __restrict__ E,
                            int* __restrict__ bbit, int n)
{
  const int i = blockIdx.x * 256 + threadIdx.x;
  if (i >= n) return;
  const float l0 = alphas[2 * i]     - logf(E[2 * i]     + 1e-5f);
  const float l1 = alphas[2 * i + 1] - logf(E[2 * i + 1] + 1e-5f);
  bbit[i] = (l0 >= l1) ? 1 : 0;
}

// ---------------- LayerNorm(X + R) * g + b ----------------
template <bool XBF>
__global__ __launch_bounds__(256) void ln_kernel(
    const void* __restrict__ Xv, const float* __restrict__ R,
    const float* __restrict__ g, const float* __restrict__ b,
    float* __restrict__ out32, bf16_t* __restrict__ out16)
{
  const long row = blockIdx.x;
  const int t = threadIdx.x;
  float x0, x1, x2, x3;
  if (XBF) {
    const bf16x4 xv = *(const bf16x4*)((const bf16_t*)Xv + row * 1024 + t * 4);
    x0 = (float)xv[0]; x1 = (float)xv[1]; x2 = (float)xv[2]; x3 = (float)xv[3];
  } else {
    const float4 xv = *(const float4*)((const float*)Xv + row * 1024 + t * 4);
    x0 = xv.x; x1 = xv.y; x2 = xv.z; x3 = xv.w;
  }
  const float4 rv = *(const float4*)(R + row * 1024 + t * 4);
  const float v0 = x0 + rv.x, v1 = x1 + rv.y, v2 = x2 + rv.z, v3 = x3 + rv.w;
  float s  = v0 + v1 + v2 + v3;
  float s2 = v0 * v0 + v1 * v1 + v2 * v2 + v3 * v3;
  s = wave_sum(s); s2 = wave_sum(s2);
  __shared__ float red[8];
  const int wv = t >> 6, lane = t & 63;
  if (lane == 0) { red[wv] = s; red[4 + wv] = s2; }
  __syncthreads();
  s  = red[0] + red[1] + red[2] + red[3];
  s2 = red[4] + red[5] + red[6] + red[7];
  const float mu = s * (1.0f / 1024.0f);
  const float var = s2 * (1.0f / 1024.0f) - mu * mu;
  const float rstd = rsqrtf(var + 1e-5f);
  const float4 gv = *(const float4*)(g + t * 4);
  const float4 bv = *(const float4*)(b + t * 4);
  float4 ov;
  ov.x = (v0 - mu) * rstd * gv.x + bv.x;
  ov.y = (v1 - mu) * rstd * gv.y + bv.y;
  ov.z = (v2 - mu) * rstd * gv.z + bv.z;
  ov.w = (v3 - mu) * rstd * gv.w + bv.w;
  if (out32) *(float4*)(out32 + row * 1024 + t * 4) = ov;
  if (out16) {
    bf16x4 oh;
    oh[0] = (bf16_t)ov.x; oh[1] = (bf16_t)ov.y; oh[2] = (bf16_t)ov.z; oh[3] = (bf16_t)ov.w;
    *(bf16x4*)(out16 + row * 1024 + t * 4) = oh;
  }
}

// ---------------- host ----------------
extern "C" void kernel_launch(void* const* d_in, const int* in_sizes, int n_in,
                              void* d_out, int out_size, void* d_ws, size_t ws_size,
                              hipStream_t stream)
{
  (void)in_sizes; (void)n_in; (void)out_size; (void)ws_size;
  const float* q_emb  = (const float*)d_in[0];
  const float* qa_emb = (const float*)d_in[1];
  const float* kW = (const float*)d_in[2];
  const float* kb = (const float*)d_in[3];
  const float* vW = (const float*)d_in[4];
  const float* vb = (const float*)d_in[5];
  const float* oW = (const float*)d_in[6];
  const float* ob = (const float*)d_in[7];
  const float* gammas = (const float*)d_in[8];
  const float* alphas = (const float*)d_in[9];
  const float* ln1_g = (const float*)d_in[10];
  const float* ln1_b = (const float*)d_in[11];
  const float* w1 = (const float*)d_in[12];
  const float* b1 = (const float*)d_in[13];
  const float* w2 = (const float*)d_in[14];
  const float* b2 = (const float*)d_in[15];
  const float* ln2_g = (const float*)d_in[16];
  const float* ln2_b = (const float*)d_in[17];
  const float* gumE = (const float*)d_in[18];
  float* outp = (float*)d_out;

  static bool attr_done = false;
  if (!attr_done) {
    attr_done = true;
    (void)hipFuncSetAttribute(reinterpret_cast<const void*>(&gemm_db<2,2,4,4,1,false,1>),
                              hipFuncAttributeMaxDynamicSharedMemorySize, 65536);
    (void)hipFuncSetAttribute(reinterpret_cast<const void*>(&gemm_db<2,2,4,4,2,false,1>),
                              hipFuncAttributeMaxDynamicSharedMemorySize, 65536);
    (void)hipFuncSetAttribute(reinterpret_cast<const void*>(&gemm_db<2,2,4,4,1,false,0>),
                              hipFuncAttributeMaxDynamicSharedMemorySize, 65536);
    (void)hipFuncSetAttribute(reinterpret_cast<const void*>(&gemm_db<2,4,8,4,1,true,1>),
                              hipFuncAttributeMaxDynamicSharedMemorySize, 131072);
  }

  // ---- workspace overlay ----
  const size_t MBc = 1ull << 20;
  char* W = (char*)d_ws;
  int*    bbit = (int*)W;
  bf16_t* VB   = (bf16_t*)(W + 1 * MBc);
  bf16_t* XB   = (bf16_t*)(W + 17 * MBc);
  bf16_t* kWb  = (bf16_t*)(W + 33 * MBc);
  bf16_t* vWb  = (bf16_t*)(W + 39 * MBc);
  bf16_t* oWb  = (bf16_t*)(W + 45 * MBc);
  bf16_t* w1b  = (bf16_t*)(W + 51 * MBc);
  bf16_t* w2b  = (bf16_t*)(W + 59 * MBc);
  bf16_t* KQB  = (bf16_t*)(W + 67 * MBc);
  bf16_t* VT   = (bf16_t*)(W + 83 * MBc);
  bf16_t* ATT  = (bf16_t*)(W + 163 * MBc);
  float*  O32  = (float*)(W + 67 * MBc);
  bf16_t* X1B  = (bf16_t*)(W + 99 * MBc);
  bf16_t* H1B  = (bf16_t*)(W + 115 * MBc);

  const long ND = 8388608;  // B*S*D

  auto run_layer = [&](int l, const void* Qin, bool qin_bf16, const bf16_t* XBp,
                       const bf16_t* VBp, bool apply_pos, int bmask,
                       float* o32, bf16_t* o16) {
    const bf16_t* kWl = kWb + (long)l * 1048576;
    const bf16_t* vWl = vWb + (long)l * 1048576;
    const bf16_t* oWl = oWb + (long)l * 1048576;
    // q==k projection -> KQB bf16 (B,S,H,DK)
    gemm_db<2,2,4,4,1,false,1><<<dim3(64, 8, 1), dim3(256), 65536, stream>>>(
        XBp, 1024, 0, 0, kWl, 1024, 0, 0, (void*)KQB, 1024, 0, 0,
        kb + l * 1024, 1, 1024, 1.0f);
    // V^T projection: per batch b, C[d,s] = sum_k vW[d,k]*X[s,k] + vb[d]
    gemm_db<2,2,4,4,2,false,1><<<dim3(8, 4, 16), dim3(256), 65536, stream>>>(
        vWl, 1024, 0, 0, VBp, 1024, 524288, 0, (void*)VT, 512, 524288, 0,
        vb + l * 1024, 1, 1024, 1.0f);
    const int zp = (bmask == 0) ? 1 : 0;
    // fused QK^T -> mid -> PV (S/P never leave LDS; Q/K/V direct from L2)
    attn_fused<<<dim3(2048), dim3(512), 0, stream>>>(
        KQB, VT, ATT, bbit + l * 4096, gammas + l * 8, bmask, zp);
    // output projection -> O32 fp32
    gemm_db<2,2,4,4,1,false,0><<<dim3(64, 8, 1), dim3(256), 65536, stream>>>(
        ATT, 1024, 0, 0, oWl, 1024, 0, 0, (void*)O32, 1024, 0, 0,
        ob + l * 1024, 1, 1024, 1.0f);
    if (!apply_pos) {
      if (qin_bf16)
        ln_kernel<true><<<dim3(8192), dim3(256), 0, stream>>>(
            Qin, O32, ln1_g + l * 1024, ln1_b + l * 1024, o32, o16);
      else
        ln_kernel<false><<<dim3(8192), dim3(256), 0, stream>>>(
            Qin, O32, ln1_g + l * 1024, ln1_b + l * 1024, o32, o16);
    } else {
      cast_kernel<<<dim3(4096), dim3(256), 0, stream>>>(w1 + (long)l * 4194304, w1b, 4194304);
      cast_kernel<<<dim3(4096), dim3(256), 0, stream>>>(w2 + (long)l * 4194304, w2b, 4194304);
      if (qin_bf16)
        ln_kernel<true><<<dim3(8192), dim3(256), 0, stream>>>(
            Qin, O32, ln1_g + l * 1024, ln1_b + l * 1024, nullptr, X1B);
      else
        ln_kernel<false><<<dim3(8192), dim3(256), 0, stream>>>(
            Qin, O32, ln1_g + l * 1024, ln1_b + l * 1024, nullptr, X1B);
      // FFN1: 256x256 tile, 8 waves, 128 KiB LDS
      gemm_db<2,4,8,4,1,true,1><<<dim3(32, 16, 1), dim3(512), 131072, stream>>>(
          X1B, 1024, 0, 0, w1b, 1024, 0, 0, (void*)H1B, 4096, 0, 0,
          b1 + l * 4096, 1, 1024, 1.0f);
      // FFN2: K=4096 deep pipeline
      gemm_db<2,2,4,4,1,false,0><<<dim3(64, 8, 1), dim3(256), 65536, stream>>>(
          H1B, 4096, 0, 0, w2b, 4096, 0, 0, (void*)O32, 1024, 0, 0,
          b2 + l * 1024, 1, 4096, 1.0f);
      ln_kernel<true><<<dim3(8192), dim3(256), 0, stream>>>(
          X1B, O32, ln2_g + l * 1024, ln2_b + l * 1024, o32, o16);
    }
  };

  // upfront: gumbel bits + qkv/o weight casts
  bbit_kernel<<<dim3(48), dim3(256), 0, stream>>>(alphas, gumE, bbit, 12288);
  cast_kernel<<<dim3(3072), dim3(256), 0, stream>>>(kW, kWb, 3145728);
  cast_kernel<<<dim3(3072), dim3(256), 0, stream>>>(vW, vWb, 3145728);
  cast_kernel<<<dim3(3072), dim3(256), 0, stream>>>(oW, oWb, 3145728);

  // layer 0: y = L0(qa, qa, qa), bmask=1, FFN. bf16(y) -> VB (layer2 values).
  cast_kernel<<<dim3(8192), dim3(256), 0, stream>>>(qa_emb, XB, ND);
  run_layer(0, qa_emb, false, XB, XB, true, 1, nullptr, VB);
  // layer 1: x = L1(q, q, q), bmask=1, no FFN. bf16(x) -> XB.
  cast_kernel<<<dim3(8192), dim3(256), 0, stream>>>(q_emb, XB, ND);
  run_layer(1, q_emb, false, XB, XB, false, 1, nullptr, XB);
  // layer 2: out = L2(x, x, y), bmask=0 (zero_pad), FFN.
  run_layer(2, XB, true, XB, VB, true, 0, outp, nullptr);
}

// Round 9
// 1090.842 us; speedup vs baseline: 1.1426x; 1.0808x over previous
//
#include <hip/hip_runtime.h>
#include <math.h>

#define NEGV -1e32f

typedef __bf16 bf16_t;
typedef _Float16 f16_t;
typedef __bf16 bf16x8 __attribute__((ext_vector_type(8)));
typedef __bf16 bf16x4 __attribute__((ext_vector_type(4)));
typedef _Float16 f16x8 __attribute__((ext_vector_type(8)));
typedef float floatx4 __attribute__((ext_vector_type(4)));

// ---------------- fast-math helpers (native transcendental pipe) ----------------
static __device__ __forceinline__ float fexp(float x) { return __expf(x); }  // v_exp_f32
#if __has_builtin(__builtin_amdgcn_sqrtf)
static __device__ __forceinline__ float fsqrt(float x) { return __builtin_amdgcn_sqrtf(x); }
#else
static __device__ __forceinline__ float fsqrt(float x) { return sqrtf(x); }
#endif
#if __has_builtin(__builtin_amdgcn_rcpf)
static __device__ __forceinline__ float frcp(float x) { return __builtin_amdgcn_rcpf(x); }
#else
static __device__ __forceinline__ float frcp(float x) { return 1.0f / x; }
#endif

// ---------------- wave helpers ----------------
static __device__ __forceinline__ float wave_sum(float v) {
#pragma unroll
  for (int d = 32; d > 0; d >>= 1) v += __shfl_xor(v, d, 64);
  return v;
}
static __device__ __forceinline__ float wave_max(float v) {
#pragma unroll
  for (int d = 32; d > 0; d >>= 1) v = fmaxf(v, __shfl_xor(v, d, 64));
  return v;
}

// async global->LDS, 16B per lane; LDS dest is wave-uniform base + lane*16
static __device__ __forceinline__ void gl2lds16(const bf16_t* g, bf16_t* l) {
  __builtin_amdgcn_global_load_lds((__attribute__((address_space(1))) void*)(void*)g,
                                   (__attribute__((address_space(3))) void*)l, 16, 0, 0);
}

// ---------------- phased pipelined GEMM: C[m,n] = alpha*sum_k A[m,k]*B[n,k] (+bias) --
// VERIFIED BEST (R2, 1106.98us total; FFN1 74.4us). Double-buffered LDS + counted
// vmcnt + phase schedule:
//   tile header: issue 2 stage rounds -> vmcnt(2) -> s_barrier (publish tile-t)
//   PH phases, each: {ds_read frag subtile | issue stage rounds | lgkmcnt(0) |
//                     setprio(1) MFMA setprio(0) | s_barrier}
// Last phase's barrier = trailing barrier: all waves' tile-t LDS reads done before
// any wave issues next tile's pre-barrier stage rounds into the other buffer.
// vmcnt never drains to 0 in the main loop (T3+T4); setprio pays on phase-split (T5).
// NOTE (R3/R4 post-mortems): barrier-between-read-and-MFMA reorder and all-header
// staging BOTH regressed — do not re-attempt incrementally.
// Swizzle: slot s of row r holds k-group s ^ (r&7), applied on the GLOBAL source
// column so global_load_lds stays lane-contiguous. Conflict-free (measured 0).
// BIAS_MODE: 0 none, 1 per-col(n), 2 per-row(m). OUT_MODE: 0 fp32, 1 bf16, 2 fp16.
template <int WM, int WN, int FM, int FN, int BIAS_MODE, bool RELU, int OUT_MODE>
__global__ __launch_bounds__(WM * WN * 64) void gemm_db(
    const bf16_t* __restrict__ A, long lda, long a_so, long a_si,
    const bf16_t* __restrict__ B, long ldb, long b_so, long b_si,
    void* __restrict__ Cv, long ldc, long c_so, long c_si,
    const float* __restrict__ bias, int zdiv, int K, float alpha)
{
  constexpr int THREADS = WM * WN * 64;
  constexpr int BM = WM * FM * 16;
  constexpr int BN = WN * FN * 16;
  constexpr int RR = THREADS / 8;   // rows staged per round (each lane = 8 cols x 16B)
  constexpr int RA = BM / RR;       // A staging rounds
  constexpr int RB = BN / RR;       // B staging rounds
  constexpr int NSTG = RA + RB;     // global_load_lds per thread per K-tile
  constexpr int MG = (FM >= 8) ? 2 : 1;  // m-groups per K-half
  constexpr int MSUB = FM / MG;          // fragments per m-group
  constexpr int PH = 2 * MG;             // phases per K-tile (2 or 4)
  extern __shared__ bf16_t smem[];
  bf16_t* const Asb = smem;                    // [2][BM*64]
  bf16_t* const Bsb = smem + 2 * (BM * 64);    // [2][BN*64]

  const int tid = threadIdx.x;
  const int wave = tid >> 6;
  const int lane = tid & 63;
  const int wm = wave / WN;
  const int wn = wave % WN;
  const int z = blockIdx.z;
  const long zo = z / zdiv;
  const long zi = z % zdiv;
  A += zo * a_so + zi * a_si;
  B += zo * b_so + zi * b_si;
  const long m0 = (long)blockIdx.x * BM;
  const long n0 = (long)blockIdx.y * BN;

  const int srow = tid >> 3;                    // row within round
  const int scol = ((tid & 7) ^ (srow & 7)) * 8;
  const bf16_t* gA = A + (m0 + srow) * lda + scol;
  const bf16_t* gB = B + (n0 + srow) * ldb + scol;
  const int lofs = wave * 512;                  // wave covers 8 rows x 64 elems / round

  floatx4 acc[FM][FN] = {};
  const int lr = lane & 15;
  const int kg = lane >> 4;
  const int NT = K >> 6;

  // staging round q (0..NSTG-1): q<RA -> A rows, else B rows. q constant at call
  // sites (unrolled), so the branch folds.
  auto stage_round = [&](int q, long ko, int dstbuf) {
    if (q < RA)
      gl2lds16(gA + (long)(q * RR) * lda + ko,
               Asb + dstbuf * (BM * 64) + lofs + q * RR * 64);
    else
      gl2lds16(gB + (long)((q - RA) * RR) * ldb + ko,
               Bsb + dstbuf * (BN * 64) + lofs + (q - RA) * RR * 64);
  };

  // prologue: tile 0 -> buf 0
#pragma unroll
  for (int q = 0; q < NSTG; ++q) stage_round(q, 0, 0);

  for (int t = 0; t < NT; ++t) {
    const int buf = t & 1;
    const bool pf = (t + 1 < NT);
    const long ko = (long)(t + 1) * 64;
    // tile header: pre-barrier stage issue is safe (prev tile's trailing barrier
    // guarantees all waves finished reading buf^1); vmcnt(2) -> my tile-t loads
    // landed; barrier publishes across waves.
    if (pf) {
#pragma unroll
      for (int q = 0; q < 2; ++q) stage_round(q, ko, buf ^ 1);
      asm volatile("s_waitcnt vmcnt(2)" ::: "memory");
    } else {
      asm volatile("s_waitcnt vmcnt(0)" ::: "memory");
    }
    __builtin_amdgcn_s_barrier();
    __builtin_amdgcn_sched_barrier(0);
    const bf16_t* __restrict__ Ab = Asb + buf * (BM * 64);
    const bf16_t* __restrict__ Bb = Bsb + buf * (BN * 64);
#pragma unroll
    for (int h = 0; h < 2; ++h) {
      const int slot = ((h * 4 + kg) ^ (lr & 7)) * 8;
      bf16x8 bfr[FN];
#pragma unroll
      for (int g = 0; g < MG; ++g) {
        const int pi = h * MG + g;
        // ds-read this phase's fragment subtile
        bf16x8 af[MSUB];
#pragma unroll
        for (int m = 0; m < MSUB; ++m)
          af[m] = *(const bf16x8*)(Ab + (wm * (FM * 16) + (g * MSUB + m) * 16 + lr) * 64 + slot);
        if (g == 0) {
#pragma unroll
          for (int n = 0; n < FN; ++n)
            bfr[n] = *(const bf16x8*)(Bb + (wn * (FN * 16) + n * 16 + lr) * 64 + slot);
        }
        // stage a slice of next tile under this phase (rounds 2..7 spread over PH)
        if (pf) {
          const int q0 = 2 + pi * 6 / PH;
          const int q1 = 2 + (pi + 1) * 6 / PH;
#pragma unroll
          for (int q = q0; q < q1; ++q) stage_round(q, ko, buf ^ 1);
        }
        asm volatile("s_waitcnt lgkmcnt(0)" ::: "memory");
        __builtin_amdgcn_sched_barrier(0);
        __builtin_amdgcn_s_setprio(1);
#pragma unroll
        for (int m = 0; m < MSUB; ++m)
#pragma unroll
          for (int n = 0; n < FN; ++n)
            acc[g * MSUB + m][n] =
                __builtin_amdgcn_mfma_f32_16x16x32_bf16(af[m], bfr[n], acc[g * MSUB + m][n], 0, 0, 0);
        __builtin_amdgcn_s_setprio(0);
        __builtin_amdgcn_sched_barrier(0);
        __builtin_amdgcn_s_barrier();   // phase boundary; last one = trailing barrier
      }
    }
  }

  // epilogue: C/D layout col=lane&15, row=(lane>>4)*4+reg (m89-verified)
  const long coff = zo * c_so + zi * c_si;
  const int q4 = (lane >> 4) * 4;
#pragma unroll
  for (int m = 0; m < FM; ++m) {
#pragma unroll
    for (int n = 0; n < FN; ++n) {
#pragma unroll
      for (int r = 0; r < 4; ++r) {
        const long row = m0 + wm * (FM * 16) + m * 16 + q4 + r;
        const long col = n0 + wn * (FN * 16) + n * 16 + lr;
        float v = acc[m][n][r] * alpha;
        if (BIAS_MODE == 1) v += bias[col];
        if (BIAS_MODE == 2) v += bias[row];
        if (RELU) v = fmaxf(v, 0.0f);
        const long idx = coff + row * ldc + col;
        if (OUT_MODE == 1)      ((bf16_t*)Cv)[idx] = (bf16_t)v;
        else if (OUT_MODE == 2) ((f16_t*)Cv)[idx]  = (f16_t)v;
        else                    ((float*)Cv)[idx]  = v;
      }
    }
  }
}

// ---------------- legacy drain-style GEMM (kept for K=128 QK^T: 2 K-tiles only,
// pipeline degenerate; higher occupancy wins there) ----------------
template <int BIAS_MODE, bool RELU, int OUT_MODE>
__global__ __launch_bounds__(256) void gemm_bt(
    const bf16_t* __restrict__ A, long lda, long a_so, long a_si,
    const bf16_t* __restrict__ B, long ldb, long b_so, long b_si,
    void* __restrict__ Cv, long ldc, long c_so, long c_si,
    const float* __restrict__ bias, int zdiv, int K, float alpha)
{
  __shared__ bf16_t As[8192];  // 128 rows x 64
  __shared__ bf16_t Bs[8192];
  const int tid = threadIdx.x;
  const int wave = tid >> 6;
  const int lane = tid & 63;
  const int wr = wave >> 1;
  const int wc = wave & 1;
  const int z = blockIdx.z;
  const long zo = z / zdiv;
  const long zi = z % zdiv;
  A += zo * a_so + zi * a_si;
  B += zo * b_so + zi * b_si;
  const long m0 = (long)blockIdx.x * 128;
  const long n0 = (long)blockIdx.y * 128;

  const int srow = tid >> 3;
  const int scol = ((tid & 7) ^ (srow & 7)) * 8;
  const bf16_t* gA = A + (m0 + srow) * lda + scol;
  const bf16_t* gB = B + (n0 + srow) * ldb + scol;
  bf16_t* lA = As + wave * 512;
  bf16_t* lB = Bs + wave * 512;

  floatx4 acc[4][4] = {};
  const int lr = lane & 15;
  const int kg = lane >> 4;

  for (int k0 = 0; k0 < K; k0 += 64) {
#pragma unroll
    for (int r = 0; r < 4; ++r) {
      gl2lds16(gA + (long)r * 32 * lda + k0, lA + r * 2048);
      gl2lds16(gB + (long)r * 32 * ldb + k0, lB + r * 2048);
    }
    __syncthreads();
#pragma unroll
    for (int h = 0; h < 2; ++h) {
      const int slot = ((h * 4 + kg) ^ (lr & 7)) * 8;
      bf16x8 af[4], bfr[4];
#pragma unroll
      for (int t = 0; t < 4; ++t) {
        af[t]  = *(const bf16x8*)(As + (wr * 64 + t * 16 + lr) * 64 + slot);
        bfr[t] = *(const bf16x8*)(Bs + (wc * 64 + t * 16 + lr) * 64 + slot);
      }
#pragma unroll
      for (int tm = 0; tm < 4; ++tm)
#pragma unroll
        for (int tn = 0; tn < 4; ++tn)
          acc[tm][tn] = __builtin_amdgcn_mfma_f32_16x16x32_bf16(af[tm], bfr[tn], acc[tm][tn], 0, 0, 0);
    }
    __syncthreads();
  }

  const long coff = zo * c_so + zi * c_si;
  const int q4 = (lane >> 4) * 4;
#pragma unroll
  for (int tm = 0; tm < 4; ++tm) {
#pragma unroll
    for (int tn = 0; tn < 4; ++tn) {
#pragma unroll
      for (int r = 0; r < 4; ++r) {
        const long row = m0 + wr * 64 + tm * 16 + q4 + r;
        const long col = n0 + wc * 64 + tn * 16 + lr;
        float v = acc[tm][tn][r] * alpha;
        if (BIAS_MODE == 1) v += bias[col];
        if (BIAS_MODE == 2) v += bias[row];
        if (RELU) v = fmaxf(v, 0.0f);
        const long idx = coff + row * ldc + col;
        if (OUT_MODE == 1)      ((bf16_t*)Cv)[idx] = (bf16_t)v;
        else if (OUT_MODE == 2) ((f16_t*)Cv)[idx]  = (f16_t)v;
        else                    ((float*)Cv)[idx]  = v;
      }
    }
  }
}

// ---------------- fp32 -> bf16 cast ----------------
__global__ __launch_bounds__(256) void cast_kernel(const float* __restrict__ in,
                                                   bf16_t* __restrict__ out, long n)
{
  const long i = ((long)blockIdx.x * 256 + threadIdx.x) * 4;
  if (i >= n) return;
  const float4 v = *(const float4*)(in + i);
  bf16x4 o;
  o[0] = (bf16_t)v.x; o[1] = (bf16_t)v.y; o[2] = (bf16_t)v.z; o[3] = (bf16_t)v.w;
  *(bf16x4*)(out + i) = o;
}

// ---------------- gumbel choice bits: b[l,h,s] = (logit0 >= logit1) ----------------
__global__ void bbit_kernel(const float* __restrict__ alphas, const float* __restrict__ E,
                            int* __restrict__ bbit, int n)
{
  const int i = blockIdx.x * 256 + threadIdx.x;
  if (i >= n) return;
  const float l0 = alphas[2 * i]     - logf(E[2 * i]     + 1e-5f);
  const float l1 = alphas[2 * i + 1] - logf(E[2 * i + 1] + 1e-5f);
  bbit[i] = (l0 >= l1) ? 1 : 0;
}

// ---------------- LayerNorm(X + R) * g + b ; one block per 1024-row ----------------
template <bool XBF>
__global__ __launch_bounds__(256) void ln_kernel(
    const void* __restrict__ Xv, const float* __restrict__ R,
    const float* __restrict__ g, const float* __restrict__ b,
    float* __restrict__ out32, bf16_t* __restrict__ out16)
{
  const long row = blockIdx.x;
  const int t = threadIdx.x;
  float x0, x1, x2, x3;
  if (XBF) {
    const bf16x4 xv = *(const bf16x4*)((const bf16_t*)Xv + row * 1024 + t * 4);
    x0 = (float)xv[0]; x1 = (float)xv[1]; x2 = (float)xv[2]; x3 = (float)xv[3];
  } else {
    const float4 xv = *(const float4*)((const float*)Xv + row * 1024 + t * 4);
    x0 = xv.x; x1 = xv.y; x2 = xv.z; x3 = xv.w;
  }
  const float4 rv = *(const float4*)(R + row * 1024 + t * 4);
  const float v0 = x0 + rv.x, v1 = x1 + rv.y, v2 = x2 + rv.z, v3 = x3 + rv.w;
  float s  = v0 + v1 + v2 + v3;
  float s2 = v0 * v0 + v1 * v1 + v2 * v2 + v3 * v3;
  s = wave_sum(s); s2 = wave_sum(s2);
  __shared__ float red[8];
  const int wv = t >> 6, lane = t & 63;
  if (lane == 0) { red[wv] = s; red[4 + wv] = s2; }
  __syncthreads();
  s  = red[0] + red[1] + red[2] + red[3];
  s2 = red[4] + red[5] + red[6] + red[7];
  const float mu = s * (1.0f / 1024.0f);
  const float var = s2 * (1.0f / 1024.0f) - mu * mu;
  const float rstd = rsqrtf(var + 1e-5f);
  const float4 gv = *(const float4*)(g + t * 4);
  const float4 bv = *(const float4*)(b + t * 4);
  float4 ov;
  ov.x = (v0 - mu) * rstd * gv.x + bv.x;
  ov.y = (v1 - mu) * rstd * gv.y + bv.y;
  ov.z = (v2 - mu) * rstd * gv.z + bv.z;
  ov.w = (v3 - mu) * rstd * gv.w + bv.w;
  if (out32) *(float4*)(out32 + row * 1024 + t * 4) = ov;
  if (out16) {
    bf16x4 oh;
    oh[0] = (bf16_t)ov.x; oh[1] = (bf16_t)ov.y; oh[2] = (bf16_t)ov.z; oh[3] = (bf16_t)ov.w;
    *(bf16x4*)(out16 + row * 1024 + t * 4) = oh;
  }
}

// ---------------- attention mid: one wave per S-row; IN-PLACE (fp16 in, bf16 out) ----
// dam[h,i,j] = (j<i+bmask) || b[h,j-i]==0 ; band = j<i+bmask
// p = softmax(dam? s : NEG); sc = band? p : 0; c = cumsum(sc); tot = sum(sc)
// te = clip(exp(sqrt(max((tot-c)*|i-j|,0)) * (-softplus(gamma_h))), 1e-5, 1e5)
// P = softmax(band? s*te : NEG); zero_pad zeroes row i==0.
// All exp/sqrt/rcp on the native transcendental pipe. UNFUSED ON PURPOSE: the
// S/P intermediates are L3-resident, and this kernel's serial shfl chains need
// full 32-wave/CU TLP — fusing into the MFMA kernel halves TLP and loses (R5-R8).
__global__ __launch_bounds__(256) void attn_mid(
    const f16_t* __restrict__ S, bf16_t* __restrict__ P,
    const int* __restrict__ bbit, const float* __restrict__ gam,
    const int bmask, const int zero_pad)
{
  const int wid = threadIdx.x >> 6;
  const int lane = threadIdx.x & 63;
  const long rowid = (long)blockIdx.x * 4 + wid;
  const int i = (int)(rowid & 511);
  const int h = (int)(rowid >> 9) & 7;
  const f16_t* s = S + rowid * 512;
  const int jb = lane * 8;

  const float gv = gam[h];
  const float gamma = -log1pf(fexp(gv));  // -softplus

  float sv[8];
  {
    const f16x8 a = *(const f16x8*)(s + jb);
#pragma unroll
    for (int u = 0; u < 8; ++u) sv[u] = (float)a[u];
  }
  const int* bb = bbit + h * 512;
  float z[8];
  bool band[8];
  float m1 = NEGV;
#pragma unroll
  for (int u = 0; u < 8; ++u) {
    const int j = jb + u;
    const bool bd = j < i + bmask;
    band[u] = bd;
    int d = j - i; d = d < 0 ? 0 : d;
    const bool allowed = bd || (bb[d] == 0);
    z[u] = allowed ? sv[u] : NEGV;
    m1 = fmaxf(m1, z[u]);
  }
  m1 = wave_max(m1);
  float e[8], es = 0.f;
#pragma unroll
  for (int u = 0; u < 8; ++u) { e[u] = fexp(z[u] - m1); es += e[u]; }
  es = wave_sum(es);
  const float inv1 = frcp(es);

  float c[8];
  float run = 0.f;
#pragma unroll
  for (int u = 0; u < 8; ++u) {
    const float p = band[u] ? e[u] * inv1 : 0.f;
    run += p;
    c[u] = run;
  }
  float x = run;
#pragma unroll
  for (int d = 1; d < 64; d <<= 1) {
    const float y = __shfl_up(x, (unsigned)d, 64);
    if (lane >= d) x += y;
  }
  const float tot = __shfl(x, 63, 64);
  const float ex = x - run;  // exclusive prefix across lanes

  float z2[8];
  float m2 = NEGV;
#pragma unroll
  for (int u = 0; u < 8; ++u) {
    const int j = jb + u;
    const float cc = c[u] + ex;
    const float pos = fabsf((float)(i - j));
    const float dist = fsqrt(fmaxf((tot - cc) * pos, 0.f));
    float te = fexp(dist * gamma);
    te = fminf(fmaxf(te, 1e-5f), 1e5f);
    z2[u] = band[u] ? sv[u] * te : NEGV;
    m2 = fmaxf(m2, z2[u]);
  }
  m2 = wave_max(m2);
  float f[8], es2 = 0.f;
#pragma unroll
  for (int u = 0; u < 8; ++u) { f[u] = fexp(z2[u] - m2); es2 += f[u]; }
  es2 = wave_sum(es2);
  const float inv2 = (zero_pad && i == 0) ? 0.f : frcp(es2);
  bf16x8 o;
#pragma unroll
  for (int u = 0; u < 8; ++u) o[u] = (bf16_t)(f[u] * inv2);
  *(bf16x8*)(P + rowid * 512 + jb) = o;
}

// ---------------- host ----------------
extern "C" void kernel_launch(void* const* d_in, const int* in_sizes, int n_in,
                              void* d_out, int out_size, void* d_ws, size_t ws_size,
                              hipStream_t stream)
{
  (void)in_sizes; (void)n_in; (void)out_size; (void)ws_size;
  const float* q_emb  = (const float*)d_in[0];
  const float* qa_emb = (const float*)d_in[1];
  const float* kW = (const float*)d_in[2];
  const float* kb = (const float*)d_in[3];
  const float* vW = (const float*)d_in[4];
  const float* vb = (const float*)d_in[5];
  const float* oW = (const float*)d_in[6];
  const float* ob = (const float*)d_in[7];
  const float* gammas = (const float*)d_in[8];
  const float* alphas = (const float*)d_in[9];
  const float* ln1_g = (const float*)d_in[10];
  const float* ln1_b = (const float*)d_in[11];
  const float* w1 = (const float*)d_in[12];
  const float* b1 = (const float*)d_in[13];
  const float* w2 = (const float*)d_in[14];
  const float* b2 = (const float*)d_in[15];
  const float* ln2_g = (const float*)d_in[16];
  const float* ln2_b = (const float*)d_in[17];
  const float* gumE = (const float*)d_in[18];
  float* outp = (float*)d_out;

  // dynamic-LDS opt-in (128-tile variants = 64 KiB, 256-tile FFN1 = 128 KiB)
  static bool attr_done = false;
  if (!attr_done) {
    attr_done = true;
    (void)hipFuncSetAttribute(reinterpret_cast<const void*>(&gemm_db<2,2,4,4,1,false,1>),
                              hipFuncAttributeMaxDynamicSharedMemorySize, 65536);
    (void)hipFuncSetAttribute(reinterpret_cast<const void*>(&gemm_db<2,2,4,4,2,false,1>),
                              hipFuncAttributeMaxDynamicSharedMemorySize, 65536);
    (void)hipFuncSetAttribute(reinterpret_cast<const void*>(&gemm_db<2,2,4,4,0,false,1>),
                              hipFuncAttributeMaxDynamicSharedMemorySize, 65536);
    (void)hipFuncSetAttribute(reinterpret_cast<const void*>(&gemm_db<2,2,4,4,1,false,0>),
                              hipFuncAttributeMaxDynamicSharedMemorySize, 65536);
    (void)hipFuncSetAttribute(reinterpret_cast<const void*>(&gemm_db<2,4,8,4,1,true,1>),
                              hipFuncAttributeMaxDynamicSharedMemorySize, 131072);
  }

  // ---- workspace overlay (peak 179 MB) ----
  const size_t MBc = 1ull << 20;
  char* W = (char*)d_ws;
  int*    bbit = (int*)W;
  bf16_t* VB   = (bf16_t*)(W + 1 * MBc);
  bf16_t* XB   = (bf16_t*)(W + 17 * MBc);
  bf16_t* kWb  = (bf16_t*)(W + 33 * MBc);
  bf16_t* vWb  = (bf16_t*)(W + 39 * MBc);
  bf16_t* oWb  = (bf16_t*)(W + 45 * MBc);
  bf16_t* w1b  = (bf16_t*)(W + 51 * MBc);
  bf16_t* w2b  = (bf16_t*)(W + 59 * MBc);
  bf16_t* KQB  = (bf16_t*)(W + 67 * MBc);
  bf16_t* VT   = (bf16_t*)(W + 83 * MBc);
  f16_t*  SSPP = (f16_t*)(W + 99 * MBc);
  bf16_t* PPb  = (bf16_t*)(W + 99 * MBc);   // bf16 view of same region
  bf16_t* ATT  = (bf16_t*)(W + 163 * MBc);
  float*  O32  = (float*)(W + 67 * MBc);
  bf16_t* X1B  = (bf16_t*)(W + 99 * MBc);
  bf16_t* H1B  = (bf16_t*)(W + 115 * MBc);

  const long ND = 8388608;  // B*S*D

  auto run_layer = [&](int l, const void* Qin, bool qin_bf16, const bf16_t* XBp,
                       const bf16_t* VBp, bool apply_pos, int bmask,
                       float* o32, bf16_t* o16) {
    const bf16_t* kWl = kWb + (long)l * 1048576;
    const bf16_t* vWl = vWb + (long)l * 1048576;
    const bf16_t* oWl = oWb + (long)l * 1048576;
    // q==k projection: (8192x1024)x(1024x1024)^T + kb -> KQB bf16 (B,S,H,DK)
    gemm_db<2,2,4,4,1,false,1><<<dim3(64, 8, 1), dim3(256), 65536, stream>>>(
        XBp, 1024, 0, 0, kWl, 1024, 0, 0, (void*)KQB, 1024, 0, 0,
        kb + l * 1024, 1, 1024, 1.0f);
    // V^T projection: per batch b, C[d,s] = sum_k vW[d,k]*X[s,k] + vb[d]
    gemm_db<2,2,4,4,2,false,1><<<dim3(8, 4, 16), dim3(256), 65536, stream>>>(
        vWl, 1024, 0, 0, VBp, 1024, 524288, 0, (void*)VT, 512, 524288, 0,
        vb + l * 1024, 1, 1024, 1.0f);
    const int zp = (bmask == 0) ? 1 : 0;
    // S = Q K^T / sqrt(128) -> fp16; K=128 (2 K-tiles) -> legacy kernel
    gemm_bt<0, false, 2><<<dim3(4, 4, 128), dim3(256), 0, stream>>>(
        KQB, 1024, 524288, 128, KQB, 1024, 524288, 128,
        (void*)SSPP, 512, 2097152, 262144, nullptr, 8, 128, 0.08838834764831845f);
    attn_mid<<<dim3(16384), dim3(256), 0, stream>>>(
        SSPP, PPb, bbit + l * 4096, gammas + l * 8, bmask, zp);
    // att = P V : A=P (512x512 bf16, in-place), B=V^T (128x512) -> ATT (B,S,H*DK)
    gemm_db<2,2,4,4,0,false,1><<<dim3(4, 1, 128), dim3(256), 65536, stream>>>(
        PPb, 512, 2097152, 262144, VT, 512, 524288, 65536,
        (void*)ATT, 1024, 524288, 128, nullptr, 8, 512, 1.0f);
    // output projection -> O32 fp32
    gemm_db<2,2,4,4,1,false,0><<<dim3(64, 8, 1), dim3(256), 65536, stream>>>(
        ATT, 1024, 0, 0, oWl, 1024, 0, 0, (void*)O32, 1024, 0, 0,
        ob + l * 1024, 1, 1024, 1.0f);
    if (!apply_pos) {
      if (qin_bf16)
        ln_kernel<true><<<dim3(8192), dim3(256), 0, stream>>>(
            Qin, O32, ln1_g + l * 1024, ln1_b + l * 1024, o32, o16);
      else
        ln_kernel<false><<<dim3(8192), dim3(256), 0, stream>>>(
            Qin, O32, ln1_g + l * 1024, ln1_b + l * 1024, o32, o16);
    } else {
      // per-layer FFN weight casts
      cast_kernel<<<dim3(4096), dim3(256), 0, stream>>>(w1 + (long)l * 4194304, w1b, 4194304);
      cast_kernel<<<dim3(4096), dim3(256), 0, stream>>>(w2 + (long)l * 4194304, w2b, 4194304);
      if (qin_bf16)
        ln_kernel<true><<<dim3(8192), dim3(256), 0, stream>>>(
            Qin, O32, ln1_g + l * 1024, ln1_b + l * 1024, nullptr, X1B);
      else
        ln_kernel<false><<<dim3(8192), dim3(256), 0, stream>>>(
            Qin, O32, ln1_g + l * 1024, ln1_b + l * 1024, nullptr, X1B);
      // FFN1: 8192x4096 @ K=1024, 256x256 tile, 8 waves, 128 KiB LDS, 4 phases
      gemm_db<2,4,8,4,1,true,1><<<dim3(32, 16, 1), dim3(512), 131072, stream>>>(
          X1B, 1024, 0, 0, w1b, 1024, 0, 0, (void*)H1B, 4096, 0, 0,
          b1 + l * 4096, 1, 1024, 1.0f);
      // FFN2: 8192x1024 @ K=4096 (deep pipeline, 64 K-tiles)
      gemm_db<2,2,4,4,1,false,0><<<dim3(64, 8, 1), dim3(256), 65536, stream>>>(
          H1B, 4096, 0, 0, w2b, 4096, 0, 0, (void*)O32, 1024, 0, 0,
          b2 + l * 1024, 1, 4096, 1.0f);
      ln_kernel<true><<<dim3(8192), dim3(256), 0, stream>>>(
          X1B, O32, ln2_g + l * 1024, ln2_b + l * 1024, o32, o16);
    }
  };

  // upfront: gumbel bits + qkv/o weight casts for all 3 layers
  bbit_kernel<<<dim3(48), dim3(256), 0, stream>>>(alphas, gumE, bbit, 12288);
  cast_kernel<<<dim3(3072), dim3(256), 0, stream>>>(kW, kWb, 3145728);
  cast_kernel<<<dim3(3072), dim3(256), 0, stream>>>(vW, vWb, 3145728);
  cast_kernel<<<dim3(3072), dim3(256), 0, stream>>>(oW, oWb, 3145728);

  // layer 0: y = L0(qa, qa, qa), bmask=1, FFN. bf16(y) -> VB (layer2 values).
  cast_kernel<<<dim3(8192), dim3(256), 0, stream>>>(qa_emb, XB, ND);
  run_layer(0, qa_emb, false, XB, XB, true, 1, nullptr, VB);
  // layer 1: x = L1(q, q, q), bmask=1, no FFN. bf16(x) -> XB (layer2 q/k + residual).
  cast_kernel<<<dim3(8192), dim3(256), 0, stream>>>(q_emb, XB, ND);
  run_layer(1, q_emb, false, XB, XB, false, 1, nullptr, XB);
  // layer 2: out = L2(x, x, y), bmask=0 (zero_pad), FFN. residual read from bf16 XB.
  run_layer(2, XB, true, XB, VB, true, 0, outp, nullptr);
}